// Round 8
// baseline (333.250 us; speedup 1.0000x reference)
//
#include <hip/hip_runtime.h>

typedef _Float16 f16x8 __attribute__((ext_vector_type(8)));
typedef _Float16 f16x4 __attribute__((ext_vector_type(4)));
typedef _Float16 f16x2 __attribute__((ext_vector_type(2)));
typedef float f32x4 __attribute__((ext_vector_type(4)));
typedef float f32x16 __attribute__((ext_vector_type(16)));

#define BN_EPS 1e-5f
#define SQRT32 5.656854249492381f
#define LOG2E  1.4426950408889634f

#define PKRTZ(a, b) __builtin_bit_cast(f16x2, __builtin_amdgcn_cvt_pkrtz((a), (b)))

// ---------------------------------------------------------------- prep (merged)
// z<16: x [b][c=384][n] fp32 -> xT_hi/lo [b][n][c] fp16 planes (transpose+split).
// z==16: weight conversion + BN affine fold.
__global__ __launch_bounds__(256) void prep(
    const float* __restrict__ x,
    const float* __restrict__ wq, const float* __restrict__ wk,
    const float* __restrict__ wv, const float* __restrict__ wp,
    const float* __restrict__ bnq, const float* __restrict__ bnk,
    const float* __restrict__ bnv, const float* __restrict__ bnp,
    _Float16* __restrict__ xT_hi, _Float16* __restrict__ xT_lo,
    _Float16* __restrict__ wqk_h, _Float16* __restrict__ wqk_l,
    _Float16* __restrict__ wv_h,  _Float16* __restrict__ wp_h,
    float* __restrict__ s_qkv, float* __restrict__ t_qkv,
    float* __restrict__ s_p,   float* __restrict__ t_p)
{
    __shared__ float Tx[64][65];
    const int t = threadIdx.x;
    if (blockIdx.z < 16) {
        const int ct = blockIdx.x, nt = blockIdx.y, b = blockIdx.z;
        const int c0 = ct * 64, n0 = nt * 64;
        {
            int tr = t >> 4, tc = (t & 15) * 4;
            #pragma unroll
            for (int p = 0; p < 4; p++) {
                int r = tr + p * 16;
                float4 v = *(const float4*)(x + ((size_t)(b * 384 + c0 + r)) * 1024 + n0 + tc);
                Tx[r][tc + 0] = v.x; Tx[r][tc + 1] = v.y; Tx[r][tc + 2] = v.z; Tx[r][tc + 3] = v.w;
            }
        }
        __syncthreads();
        {
            int nn = t >> 2, cc = (t & 3) * 16;
            f16x8 h0, h1, l0, l1;
            #pragma unroll
            for (int i = 0; i < 8; i++) {
                float v = Tx[cc + i][nn];
                _Float16 hh = (_Float16)v;
                h0[i] = hh; l0[i] = (_Float16)(v - (float)hh);
            }
            #pragma unroll
            for (int i = 0; i < 8; i++) {
                float v = Tx[cc + 8 + i][nn];
                _Float16 hh = (_Float16)v;
                h1[i] = hh; l1[i] = (_Float16)(v - (float)hh);
            }
            size_t o = ((size_t)(b * 1024 + n0 + nn)) * 384 + c0 + cc;
            *(f16x8*)(xT_hi + o) = h0; *(f16x8*)(xT_hi + o + 8) = h1;
            *(f16x8*)(xT_lo + o) = l0; *(f16x8*)(xT_lo + o + 8) = l1;
        }
    } else {
        const int NQK = 512 * 384, NV = 1024 * 384, NP = 384 * 1024;
        int tid = (blockIdx.y * 6 + blockIdx.x) * 256 + t;       // 0..24575
        for (int i = tid; i < NQK + NV + NP; i += 24576) {
            if (i < NQK) {
                int o = i / 384, c = i - o * 384;
                float v = (o < 256) ? wq[o * 384 + c] : wk[(o - 256) * 384 + c];
                _Float16 hh = (_Float16)v;
                wqk_h[i] = hh; wqk_l[i] = (_Float16)(v - (float)hh);
            } else if (i < NQK + NV) {
                wv_h[i - NQK] = (_Float16)wv[i - NQK];
            } else {
                wp_h[i - NQK - NV] = (_Float16)wp[i - NQK - NV];
            }
        }
        if (tid < 1536) {
            int i = tid;
            float g, be, m, v;
            if (i < 256)      { int o = i;       g = bnq[o]; be = bnq[256 + o];  m = bnq[512 + o];  v = bnq[768 + o]; }
            else if (i < 512) { int o = i - 256; g = bnk[o]; be = bnk[256 + o];  m = bnk[512 + o];  v = bnk[768 + o]; }
            else              { int o = i - 512; g = bnv[o]; be = bnv[1024 + o]; m = bnv[2048 + o]; v = bnv[3072 + o]; }
            float s = g * rsqrtf(v + BN_EPS);
            float tt = be - m * s;
            // fold /scale (= *sqrt(kd)) AND log2(e) (exp2 softmax) into Q's affine
            if (i < 256) { s *= SQRT32 * LOG2E; tt *= SQRT32 * LOG2E; }
            s_qkv[i] = s; t_qkv[i] = tt;
        } else if (tid < 1536 + 384) {
            int o = tid - 1536;
            float g = bnp[o], be = bnp[384 + o], m = bnp[768 + o], v = bnp[1152 + o];
            float s = g * rsqrtf(v + BN_EPS);
            s_p[o] = s; t_p[o] = be - m * s;
        }
    }
}

// ---------------------------------------------------------------- gemm_qkv
// bx<4 (Q/K rows): computes D[n][o] (transposed, 3-term hi/lo) and writes
// qT/kT [b][h][n][32] hi/lo fp16 planes directly.
// bx>=4 (V rows): D[o][n] 1-term, fp16 out, natural layout.
__global__ __launch_bounds__(256, 2) void gemm_qkv(
    const _Float16* __restrict__ wqk_h, const _Float16* __restrict__ wqk_l,
    const _Float16* __restrict__ wv_h,
    const _Float16* __restrict__ xT_hi, const _Float16* __restrict__ xT_lo,
    const float* __restrict__ S, const float* __restrict__ T,
    _Float16* __restrict__ qT_h, _Float16* __restrict__ qT_l,
    _Float16* __restrict__ kT_h, _Float16* __restrict__ kT_l,
    _Float16* __restrict__ vbuf)
{
    __shared__ __align__(16) _Float16 As_h[128 * 40];
    __shared__ __align__(16) _Float16 As_l[128 * 40];
    __shared__ __align__(16) _Float16 Bs_h[128 * 40];
    __shared__ __align__(16) _Float16 Bs_l[128 * 40];
    const int t = threadIdx.x, lane = t & 63, w = t >> 6;
    const int wr = w >> 1, wc = w & 1, l16 = lane & 15, lq = lane >> 4;
    const int bx = blockIdx.x, n0 = blockIdx.y * 128, b = blockIdx.z;
    const bool isv = bx >= 4;
    const int o0 = isv ? (bx - 4) * 128 : bx * 128;
    const _Float16* __restrict__ Ah = isv ? wv_h : wqk_h;

    f32x4 acc[4][4] = {};

    for (int kb = 0; kb < 384; kb += 32) {
        __syncthreads();
        #pragma unroll
        for (int p = 0; p < 2; p++) {
            int g = t + p * 256, row = g >> 2, ch = g & 3;
            *(uint4*)(&As_h[row * 40 + ch * 8]) =
                *(const uint4*)(Ah + (size_t)(o0 + row) * 384 + kb + ch * 8);
        }
        #pragma unroll
        for (int p = 0; p < 2; p++) {
            int g = t + p * 256, row = g >> 2, ch = g & 3;
            *(uint4*)(&Bs_h[row * 40 + ch * 8]) =
                *(const uint4*)(xT_hi + ((size_t)(b * 1024) + n0 + row) * 384 + kb + ch * 8);
        }
        if (!isv) {
            #pragma unroll
            for (int p = 0; p < 2; p++) {
                int g = t + p * 256, row = g >> 2, ch = g & 3;
                *(uint4*)(&As_l[row * 40 + ch * 8]) =
                    *(const uint4*)(wqk_l + (size_t)(o0 + row) * 384 + kb + ch * 8);
            }
            #pragma unroll
            for (int p = 0; p < 2; p++) {
                int g = t + p * 256, row = g >> 2, ch = g & 3;
                *(uint4*)(&Bs_l[row * 40 + ch * 8]) =
                    *(const uint4*)(xT_lo + ((size_t)(b * 1024) + n0 + row) * 384 + kb + ch * 8);
            }
        }
        __syncthreads();

        if (!isv) {
            // transposed: A = x tiles (n rows), B = w tiles (o cols)
            f16x8 ah[4], al[4], bh[4], bl[4];
            #pragma unroll
            for (int i = 0; i < 4; i++) {
                ah[i] = *(const f16x8*)(&Bs_h[(wr * 64 + i * 16 + l16) * 40 + lq * 8]);
                al[i] = *(const f16x8*)(&Bs_l[(wr * 64 + i * 16 + l16) * 40 + lq * 8]);
            }
            #pragma unroll
            for (int j = 0; j < 4; j++) {
                bh[j] = *(const f16x8*)(&As_h[(wc * 64 + j * 16 + l16) * 40 + lq * 8]);
                bl[j] = *(const f16x8*)(&As_l[(wc * 64 + j * 16 + l16) * 40 + lq * 8]);
            }
            #pragma unroll
            for (int i = 0; i < 4; i++)
                #pragma unroll
                for (int j = 0; j < 4; j++) {
                    acc[i][j] = __builtin_amdgcn_mfma_f32_16x16x32_f16(ah[i], bh[j], acc[i][j], 0, 0, 0);
                    acc[i][j] = __builtin_amdgcn_mfma_f32_16x16x32_f16(al[i], bh[j], acc[i][j], 0, 0, 0);
                    acc[i][j] = __builtin_amdgcn_mfma_f32_16x16x32_f16(ah[i], bl[j], acc[i][j], 0, 0, 0);
                }
        } else {
            f16x8 a[4], bf[4];
            #pragma unroll
            for (int i = 0; i < 4; i++) a[i]  = *(const f16x8*)(&As_h[(wr * 64 + i * 16 + l16) * 40 + lq * 8]);
            #pragma unroll
            for (int j = 0; j < 4; j++) bf[j] = *(const f16x8*)(&Bs_h[(wc * 64 + j * 16 + l16) * 40 + lq * 8]);
            #pragma unroll
            for (int i = 0; i < 4; i++)
                #pragma unroll
                for (int j = 0; j < 4; j++)
                    acc[i][j] = __builtin_amdgcn_mfma_f32_16x16x32_f16(a[i], bf[j], acc[i][j], 0, 0, 0);
        }
    }

    if (!isv) {
        // D[n][o]: row = n, col(l16) = o. Write qT/kT hi/lo planes directly.
        #pragma unroll
        for (int i = 0; i < 4; i++) {
            #pragma unroll
            for (int r = 0; r < 4; r++) {
                int n = n0 + wr * 64 + i * 16 + lq * 4 + r;
                #pragma unroll
                for (int j = 0; j < 4; j++) {
                    int o = o0 + wc * 64 + j * 16 + l16;
                    float sc = S[o], sh = T[o];
                    float v = acc[i][j][r] * sc + sh;
                    _Float16 hh = (_Float16)v;
                    _Float16 ll = (_Float16)(v - (float)hh);
                    int oo = o & 255;
                    size_t idx = (((size_t)(b * 8) + (oo >> 5)) * 1024 + n) * 32 + (oo & 31);
                    if (o < 256) { qT_h[idx] = hh; qT_l[idx] = ll; }
                    else         { kT_h[idx] = hh; kT_l[idx] = ll; }
                }
            }
        }
    } else {
        #pragma unroll
        for (int i = 0; i < 4; i++) {
            #pragma unroll
            for (int r = 0; r < 4; r++) {
                int o = o0 + wr * 64 + i * 16 + lq * 4 + r;
                float sc = S[512 + o], sh = T[512 + o];
                #pragma unroll
                for (int j = 0; j < 4; j++) {
                    int n = n0 + wc * 64 + j * 16 + l16;
                    vbuf[((size_t)(b * 1024) + o) * 1024 + n] = (_Float16)(acc[i][j][r] * sc + sh);
                }
            }
        }
    }
}

// ---------------------------------------------------------------- attn
// Occupancy-first flash attention. 256 thr = 4 waves, 32 q/wave (o_acc = 64
// regs/lane), 128 q/block, grid (bh=128, qt=8) = 1024 blocks.
// __launch_bounds__(256,3): 3 waves/SIMD -> 3 blocks/CU, three independent
// barrier domains hide staging latency + overlap MFMA/VALU across waves.
// K tile staged in LDS once per block (stride 36: b128 reads 2-way = free).
// V tile staged in LDS (stride 66 = 33 words/row: both uint4 staging writes
// and b64 PV reads are <=2-way = free). Single-buffered, 2 barriers/iter.
// Scores transposed D[key][q] (A=K, B=Q), 3-term hi/lo, exp2 softmax with
// ballot-gated rescale; P packed via v_cvt_pkrtz (half the cvt VALU).
__global__ __launch_bounds__(256, 3) void attn(
    const _Float16* __restrict__ qT_h, const _Float16* __restrict__ qT_l,
    const _Float16* __restrict__ kT_h, const _Float16* __restrict__ kT_l,
    const _Float16* __restrict__ vbuf,
    _Float16* __restrict__ xxT_h, _Float16* __restrict__ xxT_l)
{
    __shared__ __align__(16) _Float16 Ks_h[64 * 36];
    __shared__ __align__(16) _Float16 Ks_l[64 * 36];
    __shared__ __align__(16) _Float16 Vs[128 * 66];
    const int t = threadIdx.x, lane = t & 63, w = t >> 6;
    const int L = lane & 31, hl = lane >> 5;
    const int bh = blockIdx.x, qt = blockIdx.y;
    const int b = bh >> 3, h = bh & 7;
    const size_t vbase = ((size_t)(b * 1024) + h * 128) * 1024;
    const int q = qt * 128 + w * 32 + L;

    // Q B-frags (hi/lo planes, direct f16 loads)
    f16x8 bq_h[2], bq_l[2];
    #pragma unroll
    for (int kh = 0; kh < 2; kh++) {
        size_t base = ((size_t)(bh * 1024) + q) * 32 + kh * 16 + hl * 8;
        bq_h[kh] = *(const f16x8*)(qT_h + base);
        bq_l[kh] = *(const f16x8*)(qT_l + base);
    }

    f32x16 o_acc[4] = {};
    float m_st = -INFINITY, l_st = 0.f;

    // staging coords
    const int krow = t >> 2, kcol = (t & 3) * 8;   // K: 64 rows x 32

    for (int kt = 0; kt < 16; kt++) {
        __syncthreads();     // previous iteration's compute done
        {   // stage K tile (both planes)
            size_t src = ((size_t)(bh * 1024) + kt * 64 + krow) * 32 + kcol;
            *(uint4*)(&Ks_h[krow * 36 + kcol]) = *(const uint4*)(kT_h + src);
            *(uint4*)(&Ks_l[krow * 36 + kcol]) = *(const uint4*)(kT_l + src);
        }
        #pragma unroll
        for (int p = 0; p < 4; p++) {   // stage V tile [128 d][64 keys], stride 66
            int g2 = t + p * 256, d = g2 >> 3, kc = g2 & 7;
            *(uint4*)(&Vs[d * 66 + kc * 8]) =
                *(const uint4*)(vbuf + vbase + (size_t)d * 1024 + kt * 64 + kc * 8);
        }
        __syncthreads();

        // scores: 2 sub-tiles of 32 keys, 3-term hi/lo, K frags from LDS
        f32x16 c0, c1;
        #pragma unroll
        for (int sub = 0; sub < 2; sub++) {
            int kr = (sub * 32 + L) * 36 + hl * 8;
            f16x8 kh0 = *(const f16x8*)(&Ks_h[kr]);
            f16x8 kl0 = *(const f16x8*)(&Ks_l[kr]);
            f16x8 kh1 = *(const f16x8*)(&Ks_h[kr + 16]);
            f16x8 kl1 = *(const f16x8*)(&Ks_l[kr + 16]);
            f32x16 c = {};
            c = __builtin_amdgcn_mfma_f32_32x32x16_f16(kh0, bq_h[0], c, 0, 0, 0);
            c = __builtin_amdgcn_mfma_f32_32x32x16_f16(kl0, bq_h[0], c, 0, 0, 0);
            c = __builtin_amdgcn_mfma_f32_32x32x16_f16(kh0, bq_l[0], c, 0, 0, 0);
            c = __builtin_amdgcn_mfma_f32_32x32x16_f16(kh1, bq_h[1], c, 0, 0, 0);
            c = __builtin_amdgcn_mfma_f32_32x32x16_f16(kl1, bq_h[1], c, 0, 0, 0);
            c = __builtin_amdgcn_mfma_f32_32x32x16_f16(kh1, bq_l[1], c, 0, 0, 0);
            if (sub == 0) c0 = c; else c1 = c;
        }

        // online softmax (per-lane; one cross-lane shuffle)
        float mx = -INFINITY;
        #pragma unroll
        for (int i = 0; i < 16; i++) mx = fmaxf(mx, fmaxf(c0[i], c1[i]));
        mx = fmaxf(mx, __shfl_xor(mx, 32, 64));
        float mnew = fmaxf(m_st, mx);
        if (__any(mnew > m_st)) {                  // wave-uniform gated rescale
            float a = exp2f(m_st - mnew);
            l_st *= a;
            #pragma unroll
            for (int dt = 0; dt < 4; dt++)
                #pragma unroll
                for (int i = 0; i < 16; i++) o_acc[dt][i] *= a;
        }
        m_st = mnew;

        f16x4 pfrag[8];
        float rs = 0.f;
        #pragma unroll
        for (int qq = 0; qq < 4; qq++) {
            float p00 = exp2f(c0[qq * 4 + 0] - mnew), p01 = exp2f(c0[qq * 4 + 1] - mnew);
            float p02 = exp2f(c0[qq * 4 + 2] - mnew), p03 = exp2f(c0[qq * 4 + 3] - mnew);
            float p10 = exp2f(c1[qq * 4 + 0] - mnew), p11 = exp2f(c1[qq * 4 + 1] - mnew);
            float p12 = exp2f(c1[qq * 4 + 2] - mnew), p13 = exp2f(c1[qq * 4 + 3] - mnew);
            rs += (p00 + p01) + (p02 + p03) + (p10 + p11) + (p12 + p13);
            f16x2 a0 = PKRTZ(p00, p01);
            f16x2 a1 = PKRTZ(p02, p03);
            f16x2 b0 = PKRTZ(p10, p11);
            f16x2 b1 = PKRTZ(p12, p13);
            pfrag[qq]     = (f16x4){a0[0], a0[1], a1[0], a1[1]};
            pfrag[4 + qq] = (f16x4){b0[0], b0[1], b1[0], b1[1]};
        }
        l_st += rs;

        // O[d][q] += V * P
        #pragma unroll
        for (int slot = 0; slot < 8; slot++) {
            #pragma unroll
            for (int dt = 0; dt < 4; dt++) {
                f16x4 av = *(const f16x4*)(&Vs[(dt * 32 + L) * 66 + slot * 8 + hl * 4]);
                o_acc[dt] = __builtin_amdgcn_mfma_f32_32x32x8f16(av, pfrag[slot], o_acc[dt], 0, 0, 0);
            }
        }
    }

    l_st += __shfl_xor(l_st, 32, 64);

    // epilogue: normalize, split hi/lo, store xxT[b][n=q][d]
    float rl = 1.f / l_st;
    #pragma unroll
    for (int dt = 0; dt < 4; dt++) {
        #pragma unroll
        for (int gg = 0; gg < 4; gg++) {
            f16x4 hv, lv;
            #pragma unroll
            for (int rr = 0; rr < 4; rr++) {
                float v = o_acc[dt][gg * 4 + rr] * rl;
                _Float16 hh = (_Float16)v;
                hv[rr] = hh; lv[rr] = (_Float16)(v - (float)hh);
            }
            size_t o = ((size_t)(b * 1024) + q) * 1024 + h * 128 + dt * 32 + gg * 8 + hl * 4;
            *(f16x4*)(xxT_h + o) = hv;
            *(f16x4*)(xxT_l + o) = lv;
        }
    }
}

// ---------------------------------------------------------------- gemm_out
// out[o][n] = (sum_c Wp[o,c]*xx[c,n]) * s + t, 2-term hi/lo on xx. fp32 out.
__global__ __launch_bounds__(256, 2) void gemm_out(
    const _Float16* __restrict__ wp_h,
    const _Float16* __restrict__ xxT_h, const _Float16* __restrict__ xxT_l,
    const float* __restrict__ S, const float* __restrict__ T,
    float* __restrict__ out)
{
    __shared__ __align__(16) _Float16 As[128 * 40];
    __shared__ __align__(16) _Float16 Bh[64 * 40];
    __shared__ __align__(16) _Float16 Bl[64 * 40];
    const int t = threadIdx.x, lane = t & 63, w = t >> 6;
    const int wr = w >> 1, wc = w & 1, l16 = lane & 15, lq = lane >> 4;
    const int o0 = blockIdx.x * 128, n0 = blockIdx.y * 64, b = blockIdx.z;

    f32x4 acc[4][2] = {};

    for (int kb = 0; kb < 1024; kb += 32) {
        __syncthreads();
        #pragma unroll
        for (int p = 0; p < 2; p++) {
            int g = t + p * 256, row = g >> 2, ch = g & 3;
            *(uint4*)(&As[row * 40 + ch * 8]) =
                *(const uint4*)(wp_h + (size_t)(o0 + row) * 1024 + kb + ch * 8);
        }
        {
            int row = t >> 2, ch = t & 3;
            size_t src = ((size_t)(b * 1024) + n0 + row) * 1024 + kb + ch * 8;
            *(uint4*)(&Bh[row * 40 + ch * 8]) = *(const uint4*)(xxT_h + src);
            *(uint4*)(&Bl[row * 40 + ch * 8]) = *(const uint4*)(xxT_l + src);
        }
        __syncthreads();

        f16x8 a[4], bh[2], bl[2];
        #pragma unroll
        for (int i = 0; i < 4; i++) a[i] = *(const f16x8*)(&As[(wr * 64 + i * 16 + l16) * 40 + lq * 8]);
        #pragma unroll
        for (int j = 0; j < 2; j++) {
            bh[j] = *(const f16x8*)(&Bh[(wc * 32 + j * 16 + l16) * 40 + lq * 8]);
            bl[j] = *(const f16x8*)(&Bl[(wc * 32 + j * 16 + l16) * 40 + lq * 8]);
        }
        #pragma unroll
        for (int i = 0; i < 4; i++)
            #pragma unroll
            for (int j = 0; j < 2; j++) {
                acc[i][j] = __builtin_amdgcn_mfma_f32_16x16x32_f16(a[i], bh[j], acc[i][j], 0, 0, 0);
                acc[i][j] = __builtin_amdgcn_mfma_f32_16x16x32_f16(a[i], bl[j], acc[i][j], 0, 0, 0);
            }
    }

    #pragma unroll
    for (int i = 0; i < 4; i++) {
        #pragma unroll
        for (int r = 0; r < 4; r++) {
            int o = o0 + wr * 64 + i * 16 + lq * 4 + r;
            float sc = S[o], sh = T[o];
            #pragma unroll
            for (int j = 0; j < 2; j++) {
                int n = n0 + wc * 32 + j * 16 + l16;
                out[((size_t)(b * 384) + o) * 1024 + n] = acc[i][j][r] * sc + sh;
            }
        }
    }
}

// ---------------------------------------------------------------- launch

extern "C" void kernel_launch(void* const* d_in, const int* in_sizes, int n_in,
                              void* d_out, int out_size, void* d_ws, size_t ws_size,
                              hipStream_t stream) {
    const float* x   = (const float*)d_in[0];
    const float* wq  = (const float*)d_in[1];
    const float* bnq = (const float*)d_in[2];
    const float* wk  = (const float*)d_in[3];
    const float* bnk = (const float*)d_in[4];
    const float* wv  = (const float*)d_in[5];
    const float* bnv = (const float*)d_in[6];
    const float* wp  = (const float*)d_in[7];
    const float* bnp = (const float*)d_in[8];
    float* out = (float*)d_out;
    (void)in_sizes; (void)n_in; (void)out_size; (void)ws_size;

    char* ws = (char*)d_ws;
    size_t off = 0;
    auto alloc = [&](size_t bytes) {
        void* p = ws + off;
        off = (off + bytes + 255) & ~(size_t)255;
        return p;
    };
    // --- region A: dead after gemm_qkv; reused as xxT_h (needs >= 33.56 MB) ---
    _Float16* xT_hi = (_Float16*)alloc((size_t)16 * 1024 * 384 * 2);   // 12.58 MB
    _Float16* xT_lo = (_Float16*)alloc((size_t)16 * 1024 * 384 * 2);   // 12.58 MB
    _Float16* wqk_h = (_Float16*)alloc((size_t)512 * 384 * 2);
    _Float16* wqk_l = (_Float16*)alloc((size_t)512 * 384 * 2);
    _Float16* wv_h  = (_Float16*)alloc((size_t)1024 * 384 * 2);
    alloc((size_t)7 * 1024 * 1024);                                     // pad region A to > 33.56 MB
    _Float16* xxT_h = (_Float16*)d_ws;                                  // alias over region A
    // --- live buffers ---
    _Float16* wp_h  = (_Float16*)alloc((size_t)384 * 1024 * 2);
    float*    s_qkv = (float*)alloc(1536 * 4);
    float*    t_qkv = (float*)alloc(1536 * 4);
    float*    s_p   = (float*)alloc(384 * 4);
    float*    t_p   = (float*)alloc(384 * 4);
    _Float16* qT_h  = (_Float16*)alloc((size_t)16 * 8 * 1024 * 32 * 2); // 8.39 MB
    _Float16* qT_l  = (_Float16*)alloc((size_t)16 * 8 * 1024 * 32 * 2); // 8.39 MB
    _Float16* kT_h  = (_Float16*)alloc((size_t)16 * 8 * 1024 * 32 * 2); // 8.39 MB
    _Float16* kT_l  = (_Float16*)alloc((size_t)16 * 8 * 1024 * 32 * 2); // 8.39 MB
    _Float16* vbuf  = (_Float16*)alloc((size_t)16 * 1024 * 1024 * 2);   // 33.55 MB
    _Float16* xxT_l = (_Float16*)alloc((size_t)16 * 1024 * 1024 * 2);   // 33.55 MB

    prep<<<dim3(6, 16, 17), dim3(256), 0, stream>>>(
        x, wq, wk, wv, wp, bnq, bnk, bnv, bnp,
        xT_hi, xT_lo, wqk_h, wqk_l, wv_h, wp_h, s_qkv, t_qkv, s_p, t_p);

    gemm_qkv<<<dim3(12, 8, 16), dim3(256), 0, stream>>>(
        wqk_h, wqk_l, wv_h, xT_hi, xT_lo, s_qkv, t_qkv,
        qT_h, qT_l, kT_h, kT_l, vbuf);

    attn<<<dim3(128, 8), dim3(256), 0, stream>>>(qT_h, qT_l, kT_h, kT_l, vbuf, xxT_h, xxT_l);

    gemm_out<<<dim3(3, 16, 16), dim3(256), 0, stream>>>(wp_h, xxT_h, xxT_l, s_p, t_p, out);
}